// Round 1
// baseline (3489.961 us; speedup 1.0000x reference)
//
#include <hip/hip_runtime.h>
#include <hip/hip_bf16.h>

#define E_ 16
#define T_ 128

__device__ __forceinline__ float apply_act(float v, int act) {
  if (act == 1) return tanhf(v);
  if (act == 2) { // jax.nn.gelu approximate=True
    const float c = 0.7978845608028654f;
    return 0.5f * v * (1.0f + tanhf(c * (v + 0.044715f * v * v * v)));
  }
  return v;
}

// ---- skinny GEMM: C[128,N] = act(A[128,K] @ W[K,N] + bias), batched over e (grid.y), split-K (grid.z) ----
__global__ void __launch_bounds__(256) gemm_skinny(
    const float* __restrict__ A, const float* __restrict__ W,
    const float* __restrict__ bias, float* __restrict__ C, float* __restrict__ part,
    int N, int K, int lda, int ldc,
    long sAe, long sWe, long sBe, long sCe,
    int S, int act)
{
  int n0 = blockIdx.x * 64;
  int e  = blockIdx.y;
  int s  = blockIdx.z;
  const float* Ae = A + (long)e * sAe;
  const float* We = W + (long)e * sWe + n0;
  int kper = K / S;
  int kb = s * kper, ke = kb + kper;

  __shared__ float As[32][132];   // A-chunk transposed: As[kk][m], pad 4
  __shared__ float Ws[32][68];    // W-chunk: Ws[kk][n], pad 4
  int tid = threadIdx.x;
  int tn = tid & 15, tm = tid >> 4;
  float acc[8][4];
  #pragma unroll
  for (int i = 0; i < 8; ++i)
    #pragma unroll
    for (int j = 0; j < 4; ++j) acc[i][j] = 0.f;

  for (int k0 = kb; k0 < ke; k0 += 32) {
    #pragma unroll
    for (int i = 0; i < 4; ++i) {
      int li = i * 1024 + tid * 4;
      int r = li >> 5, kk = li & 31;
      float4 a4 = *(const float4*)(Ae + (long)r * lda + k0 + kk);
      As[kk+0][r] = a4.x; As[kk+1][r] = a4.y; As[kk+2][r] = a4.z; As[kk+3][r] = a4.w;
    }
    #pragma unroll
    for (int i = 0; i < 2; ++i) {
      int li = i * 1024 + tid * 4;
      int kk = li >> 6, j = li & 63;
      *(float4*)&Ws[kk][j] = *(const float4*)(We + (long)(k0 + kk) * N + j);
    }
    __syncthreads();
    #pragma unroll
    for (int kk = 0; kk < 32; ++kk) {
      float4 a0 = *(const float4*)&As[kk][tm*8];
      float4 a1 = *(const float4*)&As[kk][tm*8+4];
      float4 w4 = *(const float4*)&Ws[kk][tn*4];
      float av[8] = {a0.x,a0.y,a0.z,a0.w,a1.x,a1.y,a1.z,a1.w};
      float wv[4] = {w4.x,w4.y,w4.z,w4.w};
      #pragma unroll
      for (int i2 = 0; i2 < 8; ++i2)
        #pragma unroll
        for (int j2 = 0; j2 < 4; ++j2)
          acc[i2][j2] = fmaf(av[i2], wv[j2], acc[i2][j2]);
    }
    __syncthreads();
  }

  if (S == 1) {
    #pragma unroll
    for (int i2 = 0; i2 < 8; ++i2) {
      int r = tm * 8 + i2;
      float4 o; float* op = (float*)&o;
      #pragma unroll
      for (int j2 = 0; j2 < 4; ++j2)
        op[j2] = apply_act(acc[i2][j2] + bias[(long)e*sBe + n0 + tn*4 + j2], act);
      *(float4*)(C + (long)e*sCe + (long)r*ldc + n0 + tn*4) = o;
    }
  } else {
    float* pp = part + ((long)(s * gridDim.y + e) * 128) * N;
    #pragma unroll
    for (int i2 = 0; i2 < 8; ++i2) {
      int r = tm * 8 + i2;
      float4 o; float* op = (float*)&o;
      #pragma unroll
      for (int j2 = 0; j2 < 4; ++j2) op[j2] = acc[i2][j2];
      *(float4*)(pp + (long)r * N + n0 + tn*4) = o;
    }
  }
}

// reduce split-K partials + bias + act -> C
__global__ void __launch_bounds__(256) reduce_ep(
    const float* __restrict__ part, const float* __restrict__ bias, float* __restrict__ C,
    int S, int N, int ldc, long sBe, long sCe, int act, int total, int Eb)
{
  int idx = blockIdx.x * 256 + threadIdx.x;
  if (idx >= total) return;
  int n = idx % N;
  int r = (idx / N) & 127;
  int e = idx / (N * 128);
  long sstride = (long)Eb * 128 * N;
  float v = 0.f;
  for (int s = 0; s < S; ++s) v += part[s * sstride + ((long)e * 128 + r) * N + n];
  v = apply_act(v + bias[(long)e * sBe + n], act);
  C[(long)e * sCe + (long)r * ldc + n] = v;
}

// ---- sequential RNN layer: h[t] = tanh(P[t] + h[t-1] @ Wh), per-encoder 4-workgroup groups ----
// grid = 64 (E*4), block = 256. Wh slice (512 rows x 128 cols) held in 256 VGPRs/thread.
__global__ void __launch_bounds__(256, 1) rnn_seq(
    const float* __restrict__ P,     // [T][E][512], pre-activation incl. bias
    const float* __restrict__ Wh,    // + e*sWe : [512][512]
    float* __restrict__ H,           // h_all + l*512 ; element (t*E+e)*1536 + d
    int* __restrict__ ctr,           // [E], pre-zeroed, monotonic
    long sWe)
{
  int e = blockIdx.x >> 2, g = blockIdx.x & 3;
  int tid = threadIdx.x;
  int col = tid & 127;          // column within this wg's 128-col slice
  int kh  = tid >> 7;           // k-half: 0/1
  int jcol = g * 128 + col;
  __shared__ float hs[512];
  __shared__ float red[256];
  float w[256];
  const float* Wp = Wh + (long)e * sWe + (long)kh * 256 * 512 + jcol;
  #pragma unroll
  for (int k = 0; k < 256; ++k) w[k] = Wp[(long)k * 512];   // coalesced rows

  for (int t = 0; t < T_; ++t) {
    if (t == 0) {
      hs[tid] = 0.f; hs[tid + 256] = 0.f;
    } else {
      long hb = ((long)(t - 1) * E_ + e) * 1536;
      hs[tid]       = __hip_atomic_load(&H[hb + tid],       __ATOMIC_RELAXED, __HIP_MEMORY_SCOPE_AGENT);
      hs[tid + 256] = __hip_atomic_load(&H[hb + tid + 256], __ATOMIC_RELAXED, __HIP_MEMORY_SCOPE_AGENT);
    }
    __syncthreads();
    const float* hh = &hs[kh * 256];
    float acc = 0.f;
    #pragma unroll
    for (int k4 = 0; k4 < 64; ++k4) {
      float4 h4 = *(const float4*)(hh + k4 * 4);
      acc = fmaf(w[k4*4+0], h4.x, acc);
      acc = fmaf(w[k4*4+1], h4.y, acc);
      acc = fmaf(w[k4*4+2], h4.z, acc);
      acc = fmaf(w[k4*4+3], h4.w, acc);
    }
    red[tid] = acc;
    __syncthreads();
    if (tid < 128) {
      float v = red[tid] + red[tid + 128];
      v += P[((long)t * E_ + e) * 512 + jcol];
      v = tanhf(v);
      __hip_atomic_store(&H[((long)t * E_ + e) * 1536 + jcol], v, __ATOMIC_RELAXED, __HIP_MEMORY_SCOPE_AGENT);
    }
    __threadfence();
    __syncthreads();
    if (tid == 0) {
      __hip_atomic_fetch_add(&ctr[e], 1, __ATOMIC_RELEASE, __HIP_MEMORY_SCOPE_AGENT);
      int target = 4 * (t + 1);
      int guard = 0;
      while (__hip_atomic_load(&ctr[e], __ATOMIC_ACQUIRE, __HIP_MEMORY_SCOPE_AGENT) < target) {
        __builtin_amdgcn_s_sleep(2);
        if (++guard > 20000000) break;   // safety valve: fail visibly, don't hang
      }
    }
    __syncthreads();
  }
}

extern "C" void kernel_launch(void* const* d_in, const int* in_sizes, int n_in,
                              void* d_out, int out_size, void* d_ws, size_t ws_size,
                              hipStream_t stream)
{
  const float* x      = (const float*)d_in[0];
  const float* W_in0  = (const float*)d_in[1];
  const float* Wh0    = (const float*)d_in[2];
  const float* b0     = (const float*)d_in[3];
  const float* W_inr  = (const float*)d_in[4];
  const float* Wh_r   = (const float*)d_in[5];
  const float* b_r    = (const float*)d_in[6];
  const float* W_ff1  = (const float*)d_in[7];
  const float* b_ff1  = (const float*)d_in[8];
  const float* W_ff2  = (const float*)d_in[9];
  const float* b_ff2  = (const float*)d_in[10];
  const float* W_d0   = (const float*)d_in[11];
  const float* b_d0   = (const float*)d_in[12];
  const float* W_dmid = (const float*)d_in[13];
  const float* b_dmid = (const float*)d_in[14];
  const float* W_dout = (const float*)d_in[15];
  const float* b_dout = (const float*)d_in[16];
  float* ws = (float*)d_ws;

  // workspace layout (floats)
  float* h    = ws;                    // [T][E][3][512]  3,145,728
  float* P    = ws + 3145728;          // [T][E][512]     1,048,576
  float* FF   = ws + 4194304;          // [T][E][2048]    4,194,304
  float* ENC  = ws + 8388608;          // [T][E*512]      1,048,576
  float* Z0   = ws + 9437184;          // [128][2048]       262,144
  float* Z1   = ws + 9699328;
  float* Z2   = ws + 9961472;
  float* PART = ws + 10223616;         // split-K partials 2,097,152
  int*  ctr   = (int*)(ws + 12320768); // 3*E ints

  (void)in_sizes; (void)n_in; (void)out_size; (void)ws_size;
  hipMemsetAsync(ctr, 0, 3 * E_ * sizeof(int), stream);

  dim3 blk(256);
  // P = x @ W_in0 + b0
  gemm_skinny<<<dim3(8,16,1), blk, 0, stream>>>(x, W_in0, b0, P, PART,
      512, 32, 32, 8192, 0L, 16384L, 512L, 512L, 1, 0);
  // layer 0 recurrence
  rnn_seq<<<dim3(64), blk, 0, stream>>>(P, Wh0, h, ctr, 262144L);
  // P = h0 @ W_in_rest[:,0] + b_rest[:,0]
  gemm_skinny<<<dim3(8,16,1), blk, 0, stream>>>(h, W_inr, b_r, P, PART,
      512, 512, 24576, 8192, 1536L, 524288L, 1024L, 512L, 1, 0);
  rnn_seq<<<dim3(64), blk, 0, stream>>>(P, Wh_r, h + 512, ctr + 16, 524288L);
  // P = h1 @ W_in_rest[:,1] + b_rest[:,1]
  gemm_skinny<<<dim3(8,16,1), blk, 0, stream>>>(h + 512, W_inr + 262144, b_r + 512, P, PART,
      512, 512, 24576, 8192, 1536L, 524288L, 1024L, 512L, 1, 0);
  rnn_seq<<<dim3(64), blk, 0, stream>>>(P, Wh_r + 262144, h + 1024, ctr + 32, 524288L);
  // FF1: gelu(cat @ W_ff1 + b_ff1)
  gemm_skinny<<<dim3(32,16,1), blk, 0, stream>>>(h, W_ff1, b_ff1, FF, PART,
      2048, 1536, 24576, 32768, 1536L, 3145728L, 2048L, 2048L, 1, 2);
  // FF2 (split-2): ENC = FF @ W_ff2 + b_ff2
  gemm_skinny<<<dim3(8,16,2), blk, 0, stream>>>(FF, W_ff2, b_ff2, ENC, PART,
      512, 2048, 32768, 8192, 2048L, 1048576L, 512L, 512L, 2, 0);
  reduce_ep<<<dim3(4096), blk, 0, stream>>>(PART, b_ff2, ENC,
      2, 512, 8192, 512L, 512L, 0, 16*128*512, 16);
  // decoder: Z0 = tanh(ENC @ W_d0 + b_d0)   (split-8)
  gemm_skinny<<<dim3(32,1,8), blk, 0, stream>>>(ENC, W_d0, b_d0, Z0, PART,
      2048, 8192, 8192, 2048, 0L, 0L, 0L, 0L, 8, 0);
  reduce_ep<<<dim3(1024), blk, 0, stream>>>(PART, b_d0, Z0,
      8, 2048, 2048, 0L, 0L, 1, 128*2048, 1);
  // Z1 = tanh(Z0 @ W_dmid[0] + b_dmid[0])
  gemm_skinny<<<dim3(32,1,8), blk, 0, stream>>>(Z0, W_dmid, b_dmid, Z1, PART,
      2048, 2048, 2048, 2048, 0L, 0L, 0L, 0L, 8, 0);
  reduce_ep<<<dim3(1024), blk, 0, stream>>>(PART, b_dmid, Z1,
      8, 2048, 2048, 0L, 0L, 1, 128*2048, 1);
  // Z2 = tanh(Z1 @ W_dmid[1] + b_dmid[1])
  gemm_skinny<<<dim3(32,1,8), blk, 0, stream>>>(Z1, W_dmid + 4194304, b_dmid + 2048, Z2, PART,
      2048, 2048, 2048, 2048, 0L, 0L, 0L, 0L, 8, 0);
  reduce_ep<<<dim3(1024), blk, 0, stream>>>(PART, b_dmid + 2048, Z2,
      8, 2048, 2048, 0L, 0L, 1, 128*2048, 1);
  // Y = Z2 @ W_dout + b_dout -> d_out [1,128,1024]
  gemm_skinny<<<dim3(16,1,8), blk, 0, stream>>>(Z2, W_dout, b_dout, (float*)d_out, PART,
      1024, 2048, 2048, 1024, 0L, 0L, 0L, 0L, 8, 0);
  reduce_ep<<<dim3(512), blk, 0, stream>>>(PART, b_dout, (float*)d_out,
      8, 1024, 1024, 0L, 0L, 0, 128*1024, 1);
}

// Round 2
// 1753.346 us; speedup vs baseline: 1.9905x; 1.9905x over previous
//
#include <hip/hip_runtime.h>
#include <hip/hip_bf16.h>
#include <hip/hip_fp16.h>

#define E_ 16
#define T_ 128

typedef _Float16 h2_t __attribute__((ext_vector_type(2)));

__device__ __forceinline__ float fdot2u(uint32_t w, uint32_t h, float acc) {
#if __has_builtin(__builtin_amdgcn_fdot2)
  return __builtin_amdgcn_fdot2(__builtin_bit_cast(h2_t, w),
                                __builtin_bit_cast(h2_t, h), acc, false);
#else
  h2_t wv = __builtin_bit_cast(h2_t, w), hv = __builtin_bit_cast(h2_t, h);
  return acc + (float)wv.x * (float)hv.x + (float)wv.y * (float)hv.y;
#endif
}

__device__ __forceinline__ uint32_t packh2(float a, float b) {
  h2_t p; p.x = (_Float16)a; p.y = (_Float16)b;
  return __builtin_bit_cast(uint32_t, p);
}

__device__ __forceinline__ float apply_act(float v, int act) {
  if (act == 1) return tanhf(v);
  if (act == 2) { // jax.nn.gelu approximate=True
    const float c = 0.7978845608028654f;
    return 0.5f * v * (1.0f + tanhf(c * (v + 0.044715f * v * v * v)));
  }
  return v;
}

// ---- skinny GEMM: C[128,N] = act(A[128,K] @ W[K,N] + bias), batched over e (grid.y), split-K (grid.z) ----
__global__ void __launch_bounds__(256) gemm_skinny(
    const float* __restrict__ A, const float* __restrict__ W,
    const float* __restrict__ bias, float* __restrict__ C, float* __restrict__ part,
    int N, int K, int lda, int ldc,
    long sAe, long sWe, long sBe, long sCe,
    int S, int act)
{
  int n0 = blockIdx.x * 64;
  int e  = blockIdx.y;
  int s  = blockIdx.z;
  const float* Ae = A + (long)e * sAe;
  const float* We = W + (long)e * sWe + n0;
  int kper = K / S;
  int kb = s * kper, ke = kb + kper;

  __shared__ float As[32][132];   // A-chunk transposed: As[kk][m], pad 4
  __shared__ float Ws[32][68];    // W-chunk: Ws[kk][n], pad 4
  int tid = threadIdx.x;
  int tn = tid & 15, tm = tid >> 4;
  float acc[8][4];
  #pragma unroll
  for (int i = 0; i < 8; ++i)
    #pragma unroll
    for (int j = 0; j < 4; ++j) acc[i][j] = 0.f;

  for (int k0 = kb; k0 < ke; k0 += 32) {
    #pragma unroll
    for (int i = 0; i < 4; ++i) {
      int li = i * 1024 + tid * 4;
      int r = li >> 5, kk = li & 31;
      float4 a4 = *(const float4*)(Ae + (long)r * lda + k0 + kk);
      As[kk+0][r] = a4.x; As[kk+1][r] = a4.y; As[kk+2][r] = a4.z; As[kk+3][r] = a4.w;
    }
    #pragma unroll
    for (int i = 0; i < 2; ++i) {
      int li = i * 1024 + tid * 4;
      int kk = li >> 6, j = li & 63;
      *(float4*)&Ws[kk][j] = *(const float4*)(We + (long)(k0 + kk) * N + j);
    }
    __syncthreads();
    #pragma unroll
    for (int kk = 0; kk < 32; ++kk) {
      float4 a0 = *(const float4*)&As[kk][tm*8];
      float4 a1 = *(const float4*)&As[kk][tm*8+4];
      float4 w4 = *(const float4*)&Ws[kk][tn*4];
      float av[8] = {a0.x,a0.y,a0.z,a0.w,a1.x,a1.y,a1.z,a1.w};
      float wv[4] = {w4.x,w4.y,w4.z,w4.w};
      #pragma unroll
      for (int i2 = 0; i2 < 8; ++i2)
        #pragma unroll
        for (int j2 = 0; j2 < 4; ++j2)
          acc[i2][j2] = fmaf(av[i2], wv[j2], acc[i2][j2]);
    }
    __syncthreads();
  }

  if (S == 1) {
    #pragma unroll
    for (int i2 = 0; i2 < 8; ++i2) {
      int r = tm * 8 + i2;
      float4 o; float* op = (float*)&o;
      #pragma unroll
      for (int j2 = 0; j2 < 4; ++j2)
        op[j2] = apply_act(acc[i2][j2] + bias[(long)e*sBe + n0 + tn*4 + j2], act);
      *(float4*)(C + (long)e*sCe + (long)r*ldc + n0 + tn*4) = o;
    }
  } else {
    float* pp = part + ((long)(s * gridDim.y + e) * 128) * N;
    #pragma unroll
    for (int i2 = 0; i2 < 8; ++i2) {
      int r = tm * 8 + i2;
      float4 o; float* op = (float*)&o;
      #pragma unroll
      for (int j2 = 0; j2 < 4; ++j2) op[j2] = acc[i2][j2];
      *(float4*)(pp + (long)r * N + n0 + tn*4) = o;
    }
  }
}

// reduce split-K partials + bias + act -> C
__global__ void __launch_bounds__(256) reduce_ep(
    const float* __restrict__ part, const float* __restrict__ bias, float* __restrict__ C,
    int S, int N, int ldc, long sBe, long sCe, int act, int total, int Eb)
{
  int idx = blockIdx.x * 256 + threadIdx.x;
  if (idx >= total) return;
  int n = idx % N;
  int r = (idx / N) & 127;
  int e = idx / (N * 128);
  long sstride = (long)Eb * 128 * N;
  float v = 0.f;
  for (int s = 0; s < S; ++s) v += part[s * sstride + ((long)e * 128 + r) * N + n];
  v = apply_act(v + bias[(long)e * sBe + n], act);
  C[(long)e * sCe + (long)r * ldc + n] = v;
}

// ---- sequential RNN layer: h[t] = tanh(P[t] + h[t-1] @ Wh) ----
// ONE workgroup per encoder (grid=16, block=512). Thread owns one output column.
// Wh column in fp16: 208 packed pairs in VGPRs + 48 pairs in LDS. h kept in LDS
// as fp16 (double-buffered). No cross-workgroup sync; 1 barrier per step.
#define NREG_G 52   // uint4-groups (4 pairs each) held in VGPRs -> 208 regs
#define NLDS_G 12   // uint4-groups held in LDS                  -> 48*512*4 = 98304 B

__global__ void __launch_bounds__(512, 2) rnn_seq(
    const float* __restrict__ P,     // [T][E][512], pre-activation incl. bias
    const float* __restrict__ Wh,    // + e*sWe : [512][512]
    float* __restrict__ H,           // (t*E+e)*1536 + col  (layer offset applied by caller)
    long sWe)
{
  extern __shared__ uint32_t smem[];
  uint32_t* lw  = smem;                       // [NLDS_G][512][4] uints
  uint32_t* hb2 = smem + NLDS_G * 2048;       // 2 x 256 uints (512 halves each)

  int e = blockIdx.x;
  int col = threadIdx.x;
  const float* W = Wh + (long)e * sWe + col;

  uint32_t w2[NREG_G * 4];
  #pragma unroll
  for (int kp = 0; kp < NREG_G * 4; ++kp) {
    float a = W[(long)(2 * kp) * 512];
    float b = W[(long)(2 * kp + 1) * 512];
    w2[kp] = packh2(a, b);
  }
  for (int gg = 0; gg < NLDS_G; ++gg)
    #pragma unroll
    for (int i = 0; i < 4; ++i) {
      int kp = NREG_G * 4 + gg * 4 + i;
      float a = W[(long)(2 * kp) * 512];
      float b = W[(long)(2 * kp + 1) * 512];
      lw[gg * 2048 + col * 4 + i] = packh2(a, b);
    }
  if (col < 256) { hb2[col] = 0; hb2[256 + col] = 0; }
  __syncthreads();

  for (int t = 0; t < T_; ++t) {
    int cur = t & 1;
    float p = P[((long)t * E_ + e) * 512 + col];
    const uint32_t* hb = hb2 + cur * 256;
    float a0 = 0.f, a1 = 0.f, a2 = 0.f, a3 = 0.f;
    #pragma unroll
    for (int g = 0; g < NREG_G; ++g) {
      uint4 h4 = *(const uint4*)(hb + g * 4);
      a0 = fdot2u(w2[g*4+0], h4.x, a0);
      a1 = fdot2u(w2[g*4+1], h4.y, a1);
      a2 = fdot2u(w2[g*4+2], h4.z, a2);
      a3 = fdot2u(w2[g*4+3], h4.w, a3);
    }
    #pragma unroll
    for (int gg = 0; gg < NLDS_G; ++gg) {
      uint4 h4 = *(const uint4*)(hb + (NREG_G + gg) * 4);
      uint4 w4 = *(const uint4*)(lw + gg * 2048 + col * 4);
      a0 = fdot2u(w4.x, h4.x, a0);
      a1 = fdot2u(w4.y, h4.y, a1);
      a2 = fdot2u(w4.z, h4.z, a2);
      a3 = fdot2u(w4.w, h4.w, a3);
    }
    float v = tanhf((a0 + a1) + (a2 + a3) + p);
    H[((long)t * E_ + e) * 1536 + col] = v;
    _Float16* hw = (_Float16*)(hb2 + (cur ^ 1) * 256);
    hw[col] = (_Float16)v;
    __syncthreads();
  }
}

extern "C" void kernel_launch(void* const* d_in, const int* in_sizes, int n_in,
                              void* d_out, int out_size, void* d_ws, size_t ws_size,
                              hipStream_t stream)
{
  const float* x      = (const float*)d_in[0];
  const float* W_in0  = (const float*)d_in[1];
  const float* Wh0    = (const float*)d_in[2];
  const float* b0     = (const float*)d_in[3];
  const float* W_inr  = (const float*)d_in[4];
  const float* Wh_r   = (const float*)d_in[5];
  const float* b_r    = (const float*)d_in[6];
  const float* W_ff1  = (const float*)d_in[7];
  const float* b_ff1  = (const float*)d_in[8];
  const float* W_ff2  = (const float*)d_in[9];
  const float* b_ff2  = (const float*)d_in[10];
  const float* W_d0   = (const float*)d_in[11];
  const float* b_d0   = (const float*)d_in[12];
  const float* W_dmid = (const float*)d_in[13];
  const float* b_dmid = (const float*)d_in[14];
  const float* W_dout = (const float*)d_in[15];
  const float* b_dout = (const float*)d_in[16];
  float* ws = (float*)d_ws;

  // workspace layout (floats)
  float* h    = ws;                    // [T][E][3][512]  3,145,728
  float* P    = ws + 3145728;          // [T][E][512]     1,048,576
  float* FF   = ws + 4194304;          // [T][E][2048]    4,194,304
  float* ENC  = ws + 8388608;          // [T][E*512]      1,048,576
  float* Z0   = ws + 9437184;          // [128][2048]       262,144
  float* Z1   = ws + 9699328;
  float* Z2   = ws + 9961472;
  float* PART = ws + 10223616;         // split-K partials 2,097,152

  (void)in_sizes; (void)n_in; (void)out_size; (void)ws_size;

  dim3 blk(256);
  const size_t rnn_lds = (size_t)(NLDS_G * 2048 + 512) * 4;  // 100,352 B

  // P = x @ W_in0 + b0
  gemm_skinny<<<dim3(8,16,1), blk, 0, stream>>>(x, W_in0, b0, P, PART,
      512, 32, 32, 8192, 0L, 16384L, 512L, 512L, 1, 0);
  // layer 0 recurrence
  rnn_seq<<<dim3(16), dim3(512), rnn_lds, stream>>>(P, Wh0, h, 262144L);
  // P = h0 @ W_in_rest[:,0] + b_rest[:,0]
  gemm_skinny<<<dim3(8,16,1), blk, 0, stream>>>(h, W_inr, b_r, P, PART,
      512, 512, 24576, 8192, 1536L, 524288L, 1024L, 512L, 1, 0);
  rnn_seq<<<dim3(16), dim3(512), rnn_lds, stream>>>(P, Wh_r, h + 512, 524288L);
  // P = h1 @ W_in_rest[:,1] + b_rest[:,1]
  gemm_skinny<<<dim3(8,16,1), blk, 0, stream>>>(h + 512, W_inr + 262144, b_r + 512, P, PART,
      512, 512, 24576, 8192, 1536L, 524288L, 1024L, 512L, 1, 0);
  rnn_seq<<<dim3(16), dim3(512), rnn_lds, stream>>>(P, Wh_r + 262144, h + 1024, 524288L);
  // FF1: gelu(cat @ W_ff1 + b_ff1)
  gemm_skinny<<<dim3(32,16,1), blk, 0, stream>>>(h, W_ff1, b_ff1, FF, PART,
      2048, 1536, 24576, 32768, 1536L, 3145728L, 2048L, 2048L, 1, 2);
  // FF2 (split-2): ENC = FF @ W_ff2 + b_ff2
  gemm_skinny<<<dim3(8,16,2), blk, 0, stream>>>(FF, W_ff2, b_ff2, ENC, PART,
      512, 2048, 32768, 8192, 2048L, 1048576L, 512L, 512L, 2, 0);
  reduce_ep<<<dim3(4096), blk, 0, stream>>>(PART, b_ff2, ENC,
      2, 512, 8192, 512L, 512L, 0, 16*128*512, 16);
  // decoder: Z0 = tanh(ENC @ W_d0 + b_d0)   (split-8)
  gemm_skinny<<<dim3(32,1,8), blk, 0, stream>>>(ENC, W_d0, b_d0, Z0, PART,
      2048, 8192, 8192, 2048, 0L, 0L, 0L, 0L, 8, 0);
  reduce_ep<<<dim3(1024), blk, 0, stream>>>(PART, b_d0, Z0,
      8, 2048, 2048, 0L, 0L, 1, 128*2048, 1);
  // Z1 = tanh(Z0 @ W_dmid[0] + b_dmid[0])
  gemm_skinny<<<dim3(32,1,8), blk, 0, stream>>>(Z0, W_dmid, b_dmid, Z1, PART,
      2048, 2048, 2048, 2048, 0L, 0L, 0L, 0L, 8, 0);
  reduce_ep<<<dim3(1024), blk, 0, stream>>>(PART, b_dmid, Z1,
      8, 2048, 2048, 0L, 0L, 1, 128*2048, 1);
  // Z2 = tanh(Z1 @ W_dmid[1] + b_dmid[1])
  gemm_skinny<<<dim3(32,1,8), blk, 0, stream>>>(Z1, W_dmid + 4194304, b_dmid + 2048, Z2, PART,
      2048, 2048, 2048, 2048, 0L, 0L, 0L, 0L, 8, 0);
  reduce_ep<<<dim3(1024), blk, 0, stream>>>(PART, b_dmid + 2048, Z2,
      8, 2048, 2048, 0L, 0L, 1, 128*2048, 1);
  // Y = Z2 @ W_dout + b_dout -> d_out [1,128,1024]
  gemm_skinny<<<dim3(16,1,8), blk, 0, stream>>>(Z2, W_dout, b_dout, (float*)d_out, PART,
      1024, 2048, 2048, 1024, 0L, 0L, 0L, 0L, 8, 0);
  reduce_ep<<<dim3(512), blk, 0, stream>>>(PART, b_dout, (float*)d_out,
      8, 1024, 1024, 0L, 0L, 0, 128*1024, 1);
}

// Round 3
// 1662.328 us; speedup vs baseline: 2.0994x; 1.0548x over previous
//
#include <hip/hip_runtime.h>
#include <hip/hip_bf16.h>
#include <hip/hip_fp16.h>

#define E_ 16
#define T_ 128

typedef _Float16 h2_t __attribute__((ext_vector_type(2)));

__device__ __forceinline__ float fdot2u(uint32_t w, uint32_t h, float acc) {
#if __has_builtin(__builtin_amdgcn_fdot2)
  return __builtin_amdgcn_fdot2(__builtin_bit_cast(h2_t, w),
                                __builtin_bit_cast(h2_t, h), acc, false);
#else
  h2_t wv = __builtin_bit_cast(h2_t, w), hv = __builtin_bit_cast(h2_t, h);
  return acc + (float)wv.x * (float)hv.x + (float)wv.y * (float)hv.y;
#endif
}

__device__ __forceinline__ uint32_t packh2(float a, float b) {
  h2_t p; p.x = (_Float16)a; p.y = (_Float16)b;
  return __builtin_bit_cast(uint32_t, p);
}

__device__ __forceinline__ float apply_act(float v, int act) {
  if (act == 1) return tanhf(v);
  if (act == 2) { // jax.nn.gelu approximate=True
    const float c = 0.7978845608028654f;
    return 0.5f * v * (1.0f + tanhf(c * (v + 0.044715f * v * v * v)));
  }
  return v;
}

// ---- skinny GEMM: C[128,N] = act(A[128,K] @ W[K,N] + bias), batched over e (grid.y), split-K (grid.z) ----
__global__ void __launch_bounds__(256) gemm_skinny(
    const float* __restrict__ A, const float* __restrict__ W,
    const float* __restrict__ bias, float* __restrict__ C, float* __restrict__ part,
    int N, int K, int lda, int ldc,
    long sAe, long sWe, long sBe, long sCe,
    int S, int act)
{
  int n0 = blockIdx.x * 64;
  int e  = blockIdx.y;
  int s  = blockIdx.z;
  const float* Ae = A + (long)e * sAe;
  const float* We = W + (long)e * sWe + n0;
  int kper = K / S;
  int kb = s * kper, ke = kb + kper;

  __shared__ float As[32][132];   // A-chunk transposed: As[kk][m], pad 4
  __shared__ float Ws[32][68];    // W-chunk: Ws[kk][n], pad 4
  int tid = threadIdx.x;
  int tn = tid & 15, tm = tid >> 4;
  float acc[8][4];
  #pragma unroll
  for (int i = 0; i < 8; ++i)
    #pragma unroll
    for (int j = 0; j < 4; ++j) acc[i][j] = 0.f;

  for (int k0 = kb; k0 < ke; k0 += 32) {
    #pragma unroll
    for (int i = 0; i < 4; ++i) {
      int li = i * 1024 + tid * 4;
      int r = li >> 5, kk = li & 31;
      float4 a4 = *(const float4*)(Ae + (long)r * lda + k0 + kk);
      As[kk+0][r] = a4.x; As[kk+1][r] = a4.y; As[kk+2][r] = a4.z; As[kk+3][r] = a4.w;
    }
    #pragma unroll
    for (int i = 0; i < 2; ++i) {
      int li = i * 1024 + tid * 4;
      int kk = li >> 6, j = li & 63;
      *(float4*)&Ws[kk][j] = *(const float4*)(We + (long)(k0 + kk) * N + j);
    }
    __syncthreads();
    #pragma unroll
    for (int kk = 0; kk < 32; ++kk) {
      float4 a0 = *(const float4*)&As[kk][tm*8];
      float4 a1 = *(const float4*)&As[kk][tm*8+4];
      float4 w4 = *(const float4*)&Ws[kk][tn*4];
      float av[8] = {a0.x,a0.y,a0.z,a0.w,a1.x,a1.y,a1.z,a1.w};
      float wv[4] = {w4.x,w4.y,w4.z,w4.w};
      #pragma unroll
      for (int i2 = 0; i2 < 8; ++i2)
        #pragma unroll
        for (int j2 = 0; j2 < 4; ++j2)
          acc[i2][j2] = fmaf(av[i2], wv[j2], acc[i2][j2]);
    }
    __syncthreads();
  }

  if (S == 1) {
    #pragma unroll
    for (int i2 = 0; i2 < 8; ++i2) {
      int r = tm * 8 + i2;
      float4 o; float* op = (float*)&o;
      #pragma unroll
      for (int j2 = 0; j2 < 4; ++j2)
        op[j2] = apply_act(acc[i2][j2] + bias[(long)e*sBe + n0 + tn*4 + j2], act);
      *(float4*)(C + (long)e*sCe + (long)r*ldc + n0 + tn*4) = o;
    }
  } else {
    float* pp = part + ((long)(s * gridDim.y + e) * 128) * N;
    #pragma unroll
    for (int i2 = 0; i2 < 8; ++i2) {
      int r = tm * 8 + i2;
      float4 o; float* op = (float*)&o;
      #pragma unroll
      for (int j2 = 0; j2 < 4; ++j2) op[j2] = acc[i2][j2];
      *(float4*)(pp + (long)r * N + n0 + tn*4) = o;
    }
  }
}

// reduce split-K partials + bias + act -> C
__global__ void __launch_bounds__(256) reduce_ep(
    const float* __restrict__ part, const float* __restrict__ bias, float* __restrict__ C,
    int S, int N, int ldc, long sBe, long sCe, int act, int total, int Eb)
{
  int idx = blockIdx.x * 256 + threadIdx.x;
  if (idx >= total) return;
  int n = idx % N;
  int r = (idx / N) & 127;
  int e = idx / (N * 128);
  long sstride = (long)Eb * 128 * N;
  float v = 0.f;
  for (int s = 0; s < S; ++s) v += part[s * sstride + ((long)e * 128 + r) * N + n];
  v = apply_act(v + bias[(long)e * sBe + n], act);
  C[(long)e * sCe + (long)r * ldc + n] = v;
}

// ---- sequential RNN layer: h[t] = tanh(P[t] + h[t-1] @ Wh) ----
// ONE workgroup per encoder (grid=16, block=512). Thread owns one output column.
// Wh column in fp16: 200 packed pairs in VGPRs + 56 pairs in LDS. h kept in LDS
// as fp16 (double-buffered). No cross-workgroup sync; 1 barrier per step.
// amdgpu_waves_per_eu(2,2): 100+KB LDS forces 1 block/CU = 2 waves/SIMD; pin it
// so the allocator gets the full 256-VGPR/wave budget (round-2 build capped at
// 128 and spilled the weight array -> 13 MB/dispatch scratch writes).
#define NREG_G 50   // uint4-groups (4 pairs each) held in VGPRs -> 200 regs
#define NLDS_G 14   // uint4-groups held in LDS -> 56*512*4 B = 114688 B

__global__ void __launch_bounds__(512, 1) __attribute__((amdgpu_waves_per_eu(2, 2)))
rnn_seq(
    const float* __restrict__ P,     // [T][E][512], pre-activation incl. bias
    const float* __restrict__ Wh,    // + e*sWe : [512][512]
    float* __restrict__ H,           // (t*E+e)*1536 + col  (layer offset applied by caller)
    long sWe)
{
  extern __shared__ uint32_t smem[];
  uint32_t* lw  = smem;                       // [NLDS_G][512][4] uints
  uint32_t* hb2 = smem + NLDS_G * 2048;       // 2 x 256 uints (512 halves each)

  int e = blockIdx.x;
  int col = threadIdx.x;
  const float* W = Wh + (long)e * sWe + col;

  uint32_t w2[NREG_G * 4];
  #pragma unroll
  for (int kp = 0; kp < NREG_G * 4; ++kp) {
    float a = W[(long)(2 * kp) * 512];
    float b = W[(long)(2 * kp + 1) * 512];
    w2[kp] = packh2(a, b);
  }
  for (int gg = 0; gg < NLDS_G; ++gg)
    #pragma unroll
    for (int i = 0; i < 4; ++i) {
      int kp = NREG_G * 4 + gg * 4 + i;
      float a = W[(long)(2 * kp) * 512];
      float b = W[(long)(2 * kp + 1) * 512];
      lw[gg * 2048 + col * 4 + i] = packh2(a, b);
    }
  if (col < 256) { hb2[col] = 0; hb2[256 + col] = 0; }
  __syncthreads();

  for (int t = 0; t < T_; ++t) {
    int cur = t & 1;
    float p = P[((long)t * E_ + e) * 512 + col];
    const uint32_t* hb = hb2 + cur * 256;
    float a0 = 0.f, a1 = 0.f, a2 = 0.f, a3 = 0.f;
    #pragma unroll
    for (int g = 0; g < NREG_G; ++g) {
      uint4 h4 = *(const uint4*)(hb + g * 4);
      a0 = fdot2u(w2[g*4+0], h4.x, a0);
      a1 = fdot2u(w2[g*4+1], h4.y, a1);
      a2 = fdot2u(w2[g*4+2], h4.z, a2);
      a3 = fdot2u(w2[g*4+3], h4.w, a3);
    }
    #pragma unroll
    for (int gg = 0; gg < NLDS_G; ++gg) {
      uint4 h4 = *(const uint4*)(hb + (NREG_G + gg) * 4);
      uint4 w4 = *(const uint4*)(lw + gg * 2048 + col * 4);
      a0 = fdot2u(w4.x, h4.x, a0);
      a1 = fdot2u(w4.y, h4.y, a1);
      a2 = fdot2u(w4.z, h4.z, a2);
      a3 = fdot2u(w4.w, h4.w, a3);
    }
    float v = tanhf((a0 + a1) + (a2 + a3) + p);
    H[((long)t * E_ + e) * 1536 + col] = v;
    _Float16* hw = (_Float16*)(hb2 + (cur ^ 1) * 256);
    hw[col] = (_Float16)v;
    __syncthreads();
  }
}

extern "C" void kernel_launch(void* const* d_in, const int* in_sizes, int n_in,
                              void* d_out, int out_size, void* d_ws, size_t ws_size,
                              hipStream_t stream)
{
  const float* x      = (const float*)d_in[0];
  const float* W_in0  = (const float*)d_in[1];
  const float* Wh0    = (const float*)d_in[2];
  const float* b0     = (const float*)d_in[3];
  const float* W_inr  = (const float*)d_in[4];
  const float* Wh_r   = (const float*)d_in[5];
  const float* b_r    = (const float*)d_in[6];
  const float* W_ff1  = (const float*)d_in[7];
  const float* b_ff1  = (const float*)d_in[8];
  const float* W_ff2  = (const float*)d_in[9];
  const float* b_ff2  = (const float*)d_in[10];
  const float* W_d0   = (const float*)d_in[11];
  const float* b_d0   = (const float*)d_in[12];
  const float* W_dmid = (const float*)d_in[13];
  const float* b_dmid = (const float*)d_in[14];
  const float* W_dout = (const float*)d_in[15];
  const float* b_dout = (const float*)d_in[16];
  float* ws = (float*)d_ws;

  // workspace layout (floats)
  float* h    = ws;                    // [T][E][3][512]  3,145,728
  float* P    = ws + 3145728;          // [T][E][512]     1,048,576
  float* FF   = ws + 4194304;          // [T][E][2048]    4,194,304
  float* ENC  = ws + 8388608;          // [T][E*512]      1,048,576
  float* Z0   = ws + 9437184;          // [128][2048]       262,144
  float* Z1   = ws + 9699328;
  float* Z2   = ws + 9961472;
  float* PART = ws + 10223616;         // split-K partials 2,097,152

  (void)in_sizes; (void)n_in; (void)out_size; (void)ws_size;

  dim3 blk(256);
  const size_t rnn_lds = (size_t)(NLDS_G * 2048 + 512) * 4;  // 116,736 B

  // P = x @ W_in0 + b0
  gemm_skinny<<<dim3(8,16,1), blk, 0, stream>>>(x, W_in0, b0, P, PART,
      512, 32, 32, 8192, 0L, 16384L, 512L, 512L, 1, 0);
  // layer 0 recurrence
  rnn_seq<<<dim3(16), dim3(512), rnn_lds, stream>>>(P, Wh0, h, 262144L);
  // P = h0 @ W_in_rest[:,0] + b_rest[:,0]
  gemm_skinny<<<dim3(8,16,1), blk, 0, stream>>>(h, W_inr, b_r, P, PART,
      512, 512, 24576, 8192, 1536L, 524288L, 1024L, 512L, 1, 0);
  rnn_seq<<<dim3(16), dim3(512), rnn_lds, stream>>>(P, Wh_r, h + 512, 524288L);
  // P = h1 @ W_in_rest[:,1] + b_rest[:,1]
  gemm_skinny<<<dim3(8,16,1), blk, 0, stream>>>(h + 512, W_inr + 262144, b_r + 512, P, PART,
      512, 512, 24576, 8192, 1536L, 524288L, 1024L, 512L, 1, 0);
  rnn_seq<<<dim3(16), dim3(512), rnn_lds, stream>>>(P, Wh_r + 262144, h + 1024, 524288L);
  // FF1: gelu(cat @ W_ff1 + b_ff1)
  gemm_skinny<<<dim3(32,16,1), blk, 0, stream>>>(h, W_ff1, b_ff1, FF, PART,
      2048, 1536, 24576, 32768, 1536L, 3145728L, 2048L, 2048L, 1, 2);
  // FF2 (split-2): ENC = FF @ W_ff2 + b_ff2
  gemm_skinny<<<dim3(8,16,2), blk, 0, stream>>>(FF, W_ff2, b_ff2, ENC, PART,
      512, 2048, 32768, 8192, 2048L, 1048576L, 512L, 512L, 2, 0);
  reduce_ep<<<dim3(4096), blk, 0, stream>>>(PART, b_ff2, ENC,
      2, 512, 8192, 512L, 512L, 0, 16*128*512, 16);
  // decoder: Z0 = tanh(ENC @ W_d0 + b_d0)   (split-8)
  gemm_skinny<<<dim3(32,1,8), blk, 0, stream>>>(ENC, W_d0, b_d0, Z0, PART,
      2048, 8192, 8192, 2048, 0L, 0L, 0L, 0L, 8, 0);
  reduce_ep<<<dim3(1024), blk, 0, stream>>>(PART, b_d0, Z0,
      8, 2048, 2048, 0L, 0L, 1, 128*2048, 1);
  // Z1 = tanh(Z0 @ W_dmid[0] + b_dmid[0])
  gemm_skinny<<<dim3(32,1,8), blk, 0, stream>>>(Z0, W_dmid, b_dmid, Z1, PART,
      2048, 2048, 2048, 2048, 0L, 0L, 0L, 0L, 8, 0);
  reduce_ep<<<dim3(1024), blk, 0, stream>>>(PART, b_dmid, Z1,
      8, 2048, 2048, 0L, 0L, 1, 128*2048, 1);
  // Z2 = tanh(Z1 @ W_dmid[1] + b_dmid[1])
  gemm_skinny<<<dim3(32,1,8), blk, 0, stream>>>(Z1, W_dmid + 4194304, b_dmid + 2048, Z2, PART,
      2048, 2048, 2048, 2048, 0L, 0L, 0L, 0L, 8, 0);
  reduce_ep<<<dim3(1024), blk, 0, stream>>>(PART, b_dmid + 2048, Z2,
      8, 2048, 2048, 0L, 0L, 1, 128*2048, 1);
  // Y = Z2 @ W_dout + b_dout -> d_out [1,128,1024]
  gemm_skinny<<<dim3(16,1,8), blk, 0, stream>>>(Z2, W_dout, b_dout, (float*)d_out, PART,
      1024, 2048, 2048, 1024, 0L, 0L, 0L, 0L, 8, 0);
  reduce_ep<<<dim3(512), blk, 0, stream>>>(PART, b_dout, (float*)d_out,
      8, 1024, 1024, 0L, 0L, 0, 128*1024, 1);
}